// Round 7
// baseline (109.429 us; speedup 1.0000x reference)
//
#include <hip/hip_runtime.h>

#define NN 8192      // nodes
#define NE 262144    // edges
#define FIN 512
#define HIDN 256
#define NC 16

typedef __attribute__((ext_vector_type(8))) short bf16x8;   // MFMA A/B frag (4 VGPRs)
typedef __attribute__((ext_vector_type(4))) short bf16x4;
typedef __attribute__((ext_vector_type(4))) float f32x4;    // MFMA C/D frag

static __device__ __forceinline__ unsigned short f2bf(float f) {
    union { float f; unsigned u; } v; v.f = f;
    unsigned r = v.u + 0x7FFFu + ((v.u >> 16) & 1u);   // RNE
    return (unsigned short)(r >> 16);
}

// ---- pack W into bf16 MFMA B-frag order ----
// B frag (mfma_f32_16x16x32_bf16): lane holds B[k=(lane>>4)*8+j][n=lane&15], j contiguous.
// frag index f = (nt*(K/32) + kc)*64 + lane.
template<int K, int N>
static __device__ __forceinline__ void pack_w(const float* __restrict__ W,
                                              unsigned short* __restrict__ Wp, int f) {
    constexpr int KC = K / 32;
    int lane = f & 63;
    int g = f >> 6;
    int kc = g % KC;
    int nt = g / KC;
    int n = nt * 16 + (lane & 15);
    int kbase = kc * 32 + (lane >> 4) * 8;
    bf16x8 v;
#pragma unroll
    for (int j = 0; j < 8; ++j) v[j] = (short)f2bf(W[(kbase + j) * N + n]);
    *(bf16x8*)&Wp[f * 8] = v;
}

// ---- kernel A: edge-degree atomics (all blocks) + weight packing (high blocks) ----
// cnt starts at an unknown-but-uniform ws poison value `base`; atomics add on top.
// cnt[2*NN] is never touched -> canary holding `base`.
__global__ __launch_bounds__(512) void work_kernel(
    const int* __restrict__ ei,
    const float* __restrict__ W0, const float* __restrict__ W1, const float* __restrict__ W2,
    int* __restrict__ cnt,
    unsigned short* __restrict__ Wp0, unsigned short* __restrict__ Wp1,
    unsigned short* __restrict__ Wp2)
{
    const int tid = threadIdx.x, bid = blockIdx.x;
    const int gt = bid * 512 + tid;           // 0..131071 -> 2 edges each
    int2 s2 = *(const int2*)&ei[gt * 2];
    int2 t2 = *(const int2*)&ei[NE + gt * 2];
    atomicAdd(&cnt[s2.x], 1);
    atomicAdd(&cnt[s2.y], 1);
    if (s2.x == t2.x) atomicAdd(&cnt[NN + s2.x], 1);
    if (s2.y == t2.y) atomicAdd(&cnt[NN + s2.y], 1);

    if (bid >= 207) {                          // 49 blocks * 512 = 25088 frags exactly
        int gp = (bid - 207) * 512 + tid;
        if (gp < 16384)       pack_w<512, 256>(W0, Wp0, gp);
        else if (gp < 24576)  pack_w<256, 256>(W1, Wp1, gp - 16384);
        else                  pack_w<256, 16 >(W2, Wp2, gp - 24576);
    }
}

// ---- LN epilogue: v=relu(wd*acc+bias); LN over 256 cols; bf16 -> sH ----
// Lane owns rows half*16+quad*4+reg (reg 0..3), cols wq*64+nt*16+l16 (nt 0..3).
static __device__ __forceinline__ void ln_epilogue(
    const f32x4 acc[4], const float* __restrict__ bias, const float* __restrict__ gam,
    const float* __restrict__ bet, const float wdr[4],
    int half, int wq, int quad, int l16,
    unsigned short* sH, float red[][8])
{
    float bv[4], gv[4], btv[4];
#pragma unroll
    for (int nt = 0; nt < 4; ++nt) {
        int col = wq * 64 + nt * 16 + l16;
        bv[nt] = bias[col]; gv[nt] = gam[col]; btv[nt] = bet[col];
    }
    float vv[4][4], s[4], ss[4];
#pragma unroll
    for (int reg = 0; reg < 4; ++reg) {
        float ps = 0.f, pss = 0.f;
#pragma unroll
        for (int nt = 0; nt < 4; ++nt) {
            float v = fmaxf(fmaf(wdr[reg], acc[nt][reg], bv[nt]), 0.f);
            vv[nt][reg] = v;
            ps += v; pss += v * v;
        }
        s[reg] = ps; ss[reg] = pss;
    }
#pragma unroll
    for (int off = 1; off < 16; off <<= 1)
#pragma unroll
        for (int reg = 0; reg < 4; ++reg) {
            s[reg]  += __shfl_xor(s[reg],  off, 64);
            ss[reg] += __shfl_xor(ss[reg], off, 64);
        }
    __syncthreads();                       // prior sH/red reads complete
    if (l16 == 0) {
#pragma unroll
        for (int reg = 0; reg < 4; ++reg) {
            int rl = half * 16 + quad * 4 + reg;
            red[rl][wq * 2]     = s[reg];
            red[rl][wq * 2 + 1] = ss[reg];
        }
    }
    __syncthreads();
#pragma unroll
    for (int reg = 0; reg < 4; ++reg) {
        int rl = half * 16 + quad * 4 + reg;
        float ts  = red[rl][0] + red[rl][2] + red[rl][4] + red[rl][6];
        float tss = red[rl][1] + red[rl][3] + red[rl][5] + red[rl][7];
        float mu  = ts * (1.0f / 256.0f);
        float var = tss * (1.0f / 256.0f) - mu * mu;
        float rs  = rsqrtf(var + 1e-5f);
#pragma unroll
        for (int nt = 0; nt < 4; ++nt) {
            float o = (vv[nt][reg] - mu) * rs * gv[nt] + btv[nt];
            sH[rl * 264 + wq * 64 + nt * 16 + l16] = f2bf(o);
        }
    }
    __syncthreads();                       // sH ready for next phase
}

// ---- kernel B: wd from cnt, then GEMM0+LN -> GEMM1+LN -> head + log_softmax ----
// Block = 32 rows, 512 threads (8 waves). wave: half = w>>2, wq = w&3. Grid 256.
__global__ __launch_bounds__(512) void mega_kernel(
    const float* __restrict__ x,
    const unsigned short* __restrict__ Wp0, const unsigned short* __restrict__ Wp1,
    const unsigned short* __restrict__ Wp2,
    const float* __restrict__ b0, const float* __restrict__ g0, const float* __restrict__ be0,
    const float* __restrict__ b1, const float* __restrict__ g1, const float* __restrict__ be1,
    const float* __restrict__ b2, const int* __restrict__ cnt,
    float* __restrict__ out)
{
    __shared__ unsigned short sX[32 * 520];   // full 32x512 x-tile bf16 (pad 8 -> ~2-way banks)
    __shared__ unsigned short sH[32 * 264];   // h tile (32 x 256 bf16, padded)
    __shared__ float red[32][8];
    __shared__ float swd[32];

    const int tid  = threadIdx.x;
    const int lane = tid & 63, wave = tid >> 6;
    const int quad = lane >> 4, l16 = lane & 15;
    const int half = wave >> 2, wq = wave & 3;
    const int row0 = blockIdx.x * 32;

    // wd for this block's rows: counts sit on top of uniform poison `base` (canary cnt[2*NN])
    if (tid < 32) {
        int base = cnt[2 * NN];
        int d  = cnt[row0 + tid]      - base;
        int sl = cnt[NN + row0 + tid] - base;
        float u = 0.4f - (1.0f + (float)sl) / (1.0f + (float)d);
        swd[tid] = u > 0.0f ? u : 0.0f;
    }

    // ---- stage entire x tile: 2048 groups of 8 cols, 4 per thread, all loads in flight ----
    const float4* x4 = (const float4*)x;
    float4 xa[4], xb[4];
#pragma unroll
    for (int i = 0; i < 4; ++i) {
        int f8 = tid + i * 512;              // 0..2047
        int r = f8 >> 6, c8 = f8 & 63;
        xa[i] = x4[(row0 + r) * 128 + c8 * 2];
        xb[i] = x4[(row0 + r) * 128 + c8 * 2 + 1];
    }
#pragma unroll
    for (int i = 0; i < 4; ++i) {
        int f8 = tid + i * 512;
        int r = f8 >> 6, c8 = f8 & 63;
        bf16x8 h;
        h[0] = (short)f2bf(xa[i].x); h[1] = (short)f2bf(xa[i].y);
        h[2] = (short)f2bf(xa[i].z); h[3] = (short)f2bf(xa[i].w);
        h[4] = (short)f2bf(xb[i].x); h[5] = (short)f2bf(xb[i].y);
        h[6] = (short)f2bf(xb[i].z); h[7] = (short)f2bf(xb[i].w);
        *(bf16x8*)&sX[r * 520 + c8 * 8] = h;
    }
    __syncthreads();

    float wdr[4];
#pragma unroll
    for (int reg = 0; reg < 4; ++reg) wdr[reg] = swd[half * 16 + quad * 4 + reg];

    const bf16x8* Wp0v = (const bf16x8*)Wp0;
    const bf16x8* Wp1v = (const bf16x8*)Wp1;
    const bf16x8* Wp2v = (const bf16x8*)Wp2;

    // ---- layer 0: h0 = LN(relu(wd * (x @ W0) + b0)), barrier-free K loop ----
    f32x4 acc[4];
#pragma unroll
    for (int nt = 0; nt < 4; ++nt) acc[nt] = (f32x4){0.f, 0.f, 0.f, 0.f};
#pragma unroll 4
    for (int kc = 0; kc < 16; ++kc) {
        bf16x8 a = *(const bf16x8*)&sX[(half * 16 + l16) * 520 + kc * 32 + quad * 8];
#pragma unroll
        for (int nt = 0; nt < 4; ++nt) {
            bf16x8 b = Wp0v[((wq * 4 + nt) * 16 + kc) * 64 + lane];
            acc[nt] = __builtin_amdgcn_mfma_f32_16x16x32_bf16(a, b, acc[nt], 0, 0, 0);
        }
    }
    ln_epilogue(acc, b0, g0, be0, wdr, half, wq, quad, l16, sH, red);

    // ---- layer 1: h1 = LN(relu(wd * (h0 @ W1) + b1)), A from LDS ----
    f32x4 acc1[4];
#pragma unroll
    for (int nt = 0; nt < 4; ++nt) acc1[nt] = (f32x4){0.f, 0.f, 0.f, 0.f};
#pragma unroll 4
    for (int kc = 0; kc < 8; ++kc) {
        bf16x8 a = *(const bf16x8*)&sH[(half * 16 + l16) * 264 + kc * 32 + quad * 8];
#pragma unroll
        for (int nt = 0; nt < 4; ++nt) {
            bf16x8 b = Wp1v[((wq * 4 + nt) * 8 + kc) * 64 + lane];
            acc1[nt] = __builtin_amdgcn_mfma_f32_16x16x32_bf16(a, b, acc1[nt], 0, 0, 0);
        }
    }
    ln_epilogue(acc1, b1, g1, be1, wdr, half, wq, quad, l16, sH, red);

    // ---- head: emb = wd*(h1 @ W2) + b2 ; out = [emb, log_softmax(emb)] ----
    if (wq == 0) {   // waves 0 and 4 (one per row half)
        f32x4 acch = (f32x4){0.f, 0.f, 0.f, 0.f};
#pragma unroll
        for (int kc = 0; kc < 8; ++kc) {
            bf16x8 a = *(const bf16x8*)&sH[(half * 16 + l16) * 264 + kc * 32 + quad * 8];
            bf16x8 b = Wp2v[kc * 64 + lane];
            acch = __builtin_amdgcn_mfma_f32_16x16x32_bf16(a, b, acch, 0, 0, 0);
        }
        float bb = b2[l16];
#pragma unroll
        for (int reg = 0; reg < 4; ++reg) {
            int row = row0 + half * 16 + quad * 4 + reg;
            float v = fmaf(wdr[reg], acch[reg], bb);
            float m = v;
#pragma unroll
            for (int off = 8; off >= 1; off >>= 1) m = fmaxf(m, __shfl_xor(m, off, 64));
            float e = __expf(v - m);
            float se = e;
#pragma unroll
            for (int off = 8; off >= 1; off >>= 1) se += __shfl_xor(se, off, 64);
            float lsm = (v - m) - __logf(se);
            out[row * 16 + l16] = v;
            out[NN * 16 + row * 16 + l16] = lsm;
        }
    }
}

// ---------------- launch ----------------
extern "C" void kernel_launch(void* const* d_in, const int* in_sizes, int n_in,
                              void* d_out, int out_size, void* d_ws, size_t ws_size,
                              hipStream_t stream) {
    const float* x  = (const float*)d_in[0];
    const int*   ei = (const int*)d_in[1];     // int64 in reference -> int32 from harness
    const float* W0 = (const float*)d_in[2];
    const float* b0 = (const float*)d_in[3];
    const float* g0 = (const float*)d_in[4];
    const float* be0 = (const float*)d_in[5];
    const float* W1 = (const float*)d_in[6];
    const float* b1 = (const float*)d_in[7];
    const float* g1 = (const float*)d_in[8];
    const float* be1 = (const float*)d_in[9];
    const float* W2 = (const float*)d_in[10];
    const float* b2 = (const float*)d_in[11];
    float* out = (float*)d_out;

    char* ws = (char*)d_ws;
    int*            cnt = (int*)ws;                                    // 2*NN+1 ints (canary at [2*NN])
    unsigned short* Wp0 = (unsigned short*)(ws + 68 * 1024);           // 256 KB
    unsigned short* Wp1 = (unsigned short*)(ws + 324 * 1024);          // 128 KB
    unsigned short* Wp2 = (unsigned short*)(ws + 452 * 1024);          // 8 KB

    work_kernel<<<256, 512, 0, stream>>>(ei, W0, W1, W2, cnt, Wp0, Wp1, Wp2);
    mega_kernel<<<NN / 32, 512, 0, stream>>>(x, Wp0, Wp1, Wp2,
                                             b0, g0, be0, b1, g1, be1, b2, cnt, out);
}

// Round 8
// 107.028 us; speedup vs baseline: 1.0224x; 1.0224x over previous
//
#include <hip/hip_runtime.h>

#define NN 8192      // nodes
#define NE 262144    // edges
#define FIN 512
#define HIDN 256
#define NC 16

typedef __attribute__((ext_vector_type(8))) short bf16x8;   // MFMA A/B frag (4 VGPRs)
typedef __attribute__((ext_vector_type(4))) short bf16x4;
typedef __attribute__((ext_vector_type(4))) float f32x4;    // MFMA C/D frag

static __device__ __forceinline__ unsigned short f2bf(float f) {
    union { float f; unsigned u; } v; v.f = f;
    unsigned r = v.u + 0x7FFFu + ((v.u >> 16) & 1u);   // RNE
    return (unsigned short)(r >> 16);
}

// ---- pack W into bf16 MFMA B-frag order ----
// B frag (mfma_f32_16x16x32_bf16): lane holds B[k=(lane>>4)*8+j][n=lane&15], j contiguous.
// frag index f = (nt*(K/32) + kc)*64 + lane.
template<int K, int N>
static __device__ __forceinline__ void pack_w(const float* __restrict__ W,
                                              unsigned short* __restrict__ Wp, int f) {
    constexpr int KC = K / 32;
    int lane = f & 63;
    int g = f >> 6;
    int kc = g % KC;
    int nt = g / KC;
    int n = nt * 16 + (lane & 15);
    int kbase = kc * 32 + (lane >> 4) * 8;
    bf16x8 v;
#pragma unroll
    for (int j = 0; j < 8; ++j) v[j] = (short)f2bf(W[(kbase + j) * N + n]);
    *(bf16x8*)&Wp[f * 8] = v;
}

// ---- kernel A: blocks 0..206 edge-degree atomics ONLY; blocks 207..255 pack ONLY ----
// (role split: packing blocks were the stragglers when they also did edge atomics)
// cnt starts at an unknown-but-uniform ws poison value `base`; atomics add on top.
// cnt[2*NN] is never touched -> canary holding `base`.
__global__ __launch_bounds__(512) void work_kernel(
    const int* __restrict__ ei,
    const float* __restrict__ W0, const float* __restrict__ W1, const float* __restrict__ W2,
    int* __restrict__ cnt,
    unsigned short* __restrict__ Wp0, unsigned short* __restrict__ Wp1,
    unsigned short* __restrict__ Wp2)
{
    const int tid = threadIdx.x, bid = blockIdx.x;
    if (bid < 207) {
        // 207*512 = 105984 threads cover 131072 int2-chunks (2 edges each), strided
        const int p = bid * 512 + tid;
#pragma unroll
        for (int i = 0; i < 2; ++i) {
            int c = p + i * 105984;
            if (c < NE / 2) {
                int2 s2 = *(const int2*)&ei[c * 2];
                int2 t2 = *(const int2*)&ei[NE + c * 2];
                atomicAdd(&cnt[s2.x], 1);
                atomicAdd(&cnt[s2.y], 1);
                if (s2.x == t2.x) atomicAdd(&cnt[NN + s2.x], 1);
                if (s2.y == t2.y) atomicAdd(&cnt[NN + s2.y], 1);
            }
        }
    } else {                                   // 49 blocks * 512 = 25088 frags exactly
        int gp = (bid - 207) * 512 + tid;
        if (gp < 16384)       pack_w<512, 256>(W0, Wp0, gp);
        else if (gp < 24576)  pack_w<256, 256>(W1, Wp1, gp - 16384);
        else                  pack_w<256, 16 >(W2, Wp2, gp - 24576);
    }
}

// ---- LN epilogue: v=relu(wd*acc+bias); LN over 256 cols; bf16 -> sH ----
// Lane owns rows half*16+quad*4+reg (reg 0..3), cols wq*64+nt*16+l16 (nt 0..3).
static __device__ __forceinline__ void ln_epilogue(
    const f32x4 acc[4], const float* __restrict__ bias, const float* __restrict__ gam,
    const float* __restrict__ bet, const float wdr[4],
    int half, int wq, int quad, int l16,
    unsigned short* sH, float red[][8])
{
    float bv[4], gv[4], btv[4];
#pragma unroll
    for (int nt = 0; nt < 4; ++nt) {
        int col = wq * 64 + nt * 16 + l16;
        bv[nt] = bias[col]; gv[nt] = gam[col]; btv[nt] = bet[col];
    }
    float vv[4][4], s[4], ss[4];
#pragma unroll
    for (int reg = 0; reg < 4; ++reg) {
        float ps = 0.f, pss = 0.f;
#pragma unroll
        for (int nt = 0; nt < 4; ++nt) {
            float v = fmaxf(fmaf(wdr[reg], acc[nt][reg], bv[nt]), 0.f);
            vv[nt][reg] = v;
            ps += v; pss += v * v;
        }
        s[reg] = ps; ss[reg] = pss;
    }
#pragma unroll
    for (int off = 1; off < 16; off <<= 1)
#pragma unroll
        for (int reg = 0; reg < 4; ++reg) {
            s[reg]  += __shfl_xor(s[reg],  off, 64);
            ss[reg] += __shfl_xor(ss[reg], off, 64);
        }
    __syncthreads();                       // prior sH/red reads complete
    if (l16 == 0) {
#pragma unroll
        for (int reg = 0; reg < 4; ++reg) {
            int rl = half * 16 + quad * 4 + reg;
            red[rl][wq * 2]     = s[reg];
            red[rl][wq * 2 + 1] = ss[reg];
        }
    }
    __syncthreads();
#pragma unroll
    for (int reg = 0; reg < 4; ++reg) {
        int rl = half * 16 + quad * 4 + reg;
        float ts  = red[rl][0] + red[rl][2] + red[rl][4] + red[rl][6];
        float tss = red[rl][1] + red[rl][3] + red[rl][5] + red[rl][7];
        float mu  = ts * (1.0f / 256.0f);
        float var = tss * (1.0f / 256.0f) - mu * mu;
        float rs  = rsqrtf(var + 1e-5f);
#pragma unroll
        for (int nt = 0; nt < 4; ++nt) {
            float o = (vv[nt][reg] - mu) * rs * gv[nt] + btv[nt];
            sH[rl * 264 + wq * 64 + nt * 16 + l16] = f2bf(o);
        }
    }
    __syncthreads();                       // sH ready for next phase
}

// ---- kernel B: wd from cnt, then GEMM0+LN -> GEMM1+LN -> head + log_softmax ----
// Block = 32 rows, 512 threads (8 waves). wave: half = w>>2, wq = w&3. Grid 256.
__global__ __launch_bounds__(512) void mega_kernel(
    const float* __restrict__ x,
    const unsigned short* __restrict__ Wp0, const unsigned short* __restrict__ Wp1,
    const unsigned short* __restrict__ Wp2,
    const float* __restrict__ b0, const float* __restrict__ g0, const float* __restrict__ be0,
    const float* __restrict__ b1, const float* __restrict__ g1, const float* __restrict__ be1,
    const float* __restrict__ b2, const int* __restrict__ cnt,
    float* __restrict__ out)
{
    __shared__ unsigned short sX[32 * 136];   // 128-k staging chunk (pad -> 2-way banks, free)
    __shared__ unsigned short sH[32 * 264];   // h tile (32 x 256 bf16, padded)
    __shared__ float red[32][8];
    __shared__ float swd[32];

    const int tid  = threadIdx.x;
    const int lane = tid & 63, wave = tid >> 6;
    const int quad = lane >> 4, l16 = lane & 15;
    const int half = wave >> 2, wq = wave & 3;
    const int row0 = blockIdx.x * 32;

    // wd for this block's rows: counts sit on top of uniform poison `base` (canary cnt[2*NN])
    if (tid < 32) {
        int base = cnt[2 * NN];
        int d  = cnt[row0 + tid]      - base;
        int sl = cnt[NN + row0 + tid] - base;
        float u = 0.4f - (1.0f + (float)sl) / (1.0f + (float)d);
        swd[tid] = u > 0.0f ? u : 0.0f;
    }
    __syncthreads();
    float wdr[4];
#pragma unroll
    for (int reg = 0; reg < 4; ++reg) wdr[reg] = swd[half * 16 + quad * 4 + reg];

    const bf16x8* Wp0v = (const bf16x8*)Wp0;
    const bf16x8* Wp1v = (const bf16x8*)Wp1;
    const bf16x8* Wp2v = (const bf16x8*)Wp2;
    const float4* x4 = (const float4*)x;

    // ---- layer 0: h0 = LN(relu(wd * (x @ W0) + b0)) ----
    f32x4 acc[4];
#pragma unroll
    for (int nt = 0; nt < 4; ++nt) acc[nt] = (f32x4){0.f, 0.f, 0.f, 0.f};

    for (int kb = 0; kb < 4; ++kb) {
#pragma unroll
        for (int i = 0; i < 2; ++i) {
            int f = tid + i * 512;           // 0..1023
            int r = f >> 5, c4 = f & 31;
            float4 v = x4[(row0 + r) * 128 + kb * 32 + c4];
            bf16x4 h;
            h[0] = (short)f2bf(v.x); h[1] = (short)f2bf(v.y);
            h[2] = (short)f2bf(v.z); h[3] = (short)f2bf(v.w);
            *(bf16x4*)&sX[r * 136 + c4 * 4] = h;
        }
        __syncthreads();
#pragma unroll
        for (int kc = 0; kc < 4; ++kc) {
            bf16x8 a = *(const bf16x8*)&sX[(half * 16 + l16) * 136 + kc * 32 + quad * 8];
#pragma unroll
            for (int nt = 0; nt < 4; ++nt) {
                bf16x8 b = Wp0v[((wq * 4 + nt) * 16 + kb * 4 + kc) * 64 + lane];
                acc[nt] = __builtin_amdgcn_mfma_f32_16x16x32_bf16(a, b, acc[nt], 0, 0, 0);
            }
        }
        __syncthreads();
    }
    ln_epilogue(acc, b0, g0, be0, wdr, half, wq, quad, l16, sH, red);

    // ---- layer 1: h1 = LN(relu(wd * (h0 @ W1) + b1)), A from LDS ----
    f32x4 acc1[4];
#pragma unroll
    for (int nt = 0; nt < 4; ++nt) acc1[nt] = (f32x4){0.f, 0.f, 0.f, 0.f};
#pragma unroll
    for (int kc = 0; kc < 8; ++kc) {
        bf16x8 a = *(const bf16x8*)&sH[(half * 16 + l16) * 264 + kc * 32 + quad * 8];
#pragma unroll
        for (int nt = 0; nt < 4; ++nt) {
            bf16x8 b = Wp1v[((wq * 4 + nt) * 8 + kc) * 64 + lane];
            acc1[nt] = __builtin_amdgcn_mfma_f32_16x16x32_bf16(a, b, acc1[nt], 0, 0, 0);
        }
    }
    ln_epilogue(acc1, b1, g1, be1, wdr, half, wq, quad, l16, sH, red);

    // ---- head: emb = wd*(h1 @ W2) + b2 ; out = [emb, log_softmax(emb)] ----
    if (wq == 0) {   // waves 0 and 4 (one per row half)
        f32x4 acch = (f32x4){0.f, 0.f, 0.f, 0.f};
#pragma unroll
        for (int kc = 0; kc < 8; ++kc) {
            bf16x8 a = *(const bf16x8*)&sH[(half * 16 + l16) * 264 + kc * 32 + quad * 8];
            bf16x8 b = Wp2v[kc * 64 + lane];
            acch = __builtin_amdgcn_mfma_f32_16x16x32_bf16(a, b, acch, 0, 0, 0);
        }
        float bb = b2[l16];
#pragma unroll
        for (int reg = 0; reg < 4; ++reg) {
            int row = row0 + half * 16 + quad * 4 + reg;
            float v = fmaf(wdr[reg], acch[reg], bb);
            float m = v;
#pragma unroll
            for (int off = 8; off >= 1; off >>= 1) m = fmaxf(m, __shfl_xor(m, off, 64));
            float e = __expf(v - m);
            float se = e;
#pragma unroll
            for (int off = 8; off >= 1; off >>= 1) se += __shfl_xor(se, off, 64);
            float lsm = (v - m) - __logf(se);
            out[row * 16 + l16] = v;
            out[NN * 16 + row * 16 + l16] = lsm;
        }
    }
}

// ---------------- launch ----------------
extern "C" void kernel_launch(void* const* d_in, const int* in_sizes, int n_in,
                              void* d_out, int out_size, void* d_ws, size_t ws_size,
                              hipStream_t stream) {
    const float* x  = (const float*)d_in[0];
    const int*   ei = (const int*)d_in[1];     // int64 in reference -> int32 from harness
    const float* W0 = (const float*)d_in[2];
    const float* b0 = (const float*)d_in[3];
    const float* g0 = (const float*)d_in[4];
    const float* be0 = (const float*)d_in[5];
    const float* W1 = (const float*)d_in[6];
    const float* b1 = (const float*)d_in[7];
    const float* g1 = (const float*)d_in[8];
    const float* be1 = (const float*)d_in[9];
    const float* W2 = (const float*)d_in[10];
    const float* b2 = (const float*)d_in[11];
    float* out = (float*)d_out;

    char* ws = (char*)d_ws;
    int*            cnt = (int*)ws;                                    // 2*NN+1 ints (canary at [2*NN])
    unsigned short* Wp0 = (unsigned short*)(ws + 68 * 1024);           // 256 KB
    unsigned short* Wp1 = (unsigned short*)(ws + 324 * 1024);          // 128 KB
    unsigned short* Wp2 = (unsigned short*)(ws + 452 * 1024);          // 8 KB

    work_kernel<<<256, 512, 0, stream>>>(ei, W0, W1, W2, cnt, Wp0, Wp1, Wp2);
    mega_kernel<<<NN / 32, 512, 0, stream>>>(x, Wp0, Wp1, Wp2,
                                             b0, g0, be0, b1, g1, be1, b2, cnt, out);
}